// Round 4
// baseline (606.085 us; speedup 1.0000x reference)
//
#include <hip/hip_runtime.h>
#include <hip/hip_bf16.h>

#define M_LEN 1024
#define BATCH 16384

// fallback kernel tiling
#define BM 128
#define BN 128
#define BK 64
#define THREADS 256

// main fused tiling (256^2, 8 waves)
#define BM2 256
#define BN2 256
#define GTHREADS 512

typedef __attribute__((ext_vector_type(8))) short bf16x8;
typedef __attribute__((ext_vector_type(4))) float f32x4;
typedef unsigned short ushort_t;

// ---------------- helpers ----------------

// fp32 -> bf16 RNE (scalar; prologue + fallback)
__device__ __forceinline__ ushort_t bf16_rne(float f) {
    unsigned u = __float_as_uint(f);
    unsigned r = u + 0x7FFFu + ((u >> 16) & 1u);
    return (ushort_t)(r >> 16);
}

// pack two fp32 -> two bf16 (RTZ) in one v_perm_b32 (fallback kernel only)
__device__ __forceinline__ unsigned pack2(float lo, float hi) {
    return __builtin_amdgcn_perm(__float_as_uint(hi), __float_as_uint(lo), 0x07060302u);
}

// async global->LDS, 16B per lane. LDS dest is wave-uniform base + lane*16.
__device__ __forceinline__ void gload_lds16(const void* g, void* l) {
    __builtin_amdgcn_global_load_lds(
        (const __attribute__((address_space(1))) unsigned int*)g,
        (__attribute__((address_space(3))) unsigned int*)l,
        16, 0, 0);
}

// ---------------- prologue: W fp32 -> bf16 (4 MB read, 2 MB write, ~4 us) -------
__global__ __launch_bounds__(THREADS) void convert_w(
    const float* __restrict__ W, ushort_t* __restrict__ Wb)
{
    const int wave = threadIdx.x >> 6;
    const int lane = threadIdx.x & 63;
    const int r = blockIdx.x * 4 + wave;          // grid = 256 -> rows 0..1023
    const float4* row = (const float4*)(W + (size_t)r * M_LEN);
    ushort_t* dst = Wb + (size_t)r * M_LEN;
    #pragma unroll
    for (int j = 0; j < 4; ++j) {
        float4 v = row[j * 64 + lane];
        ushort4 o;
        o.x = bf16_rne(v.x); o.y = bf16_rne(v.y);
        o.z = bf16_rne(v.z); o.w = bf16_rne(v.w);
        ((ushort4*)dst)[j * 64 + lane] = o;
    }
}

// ---------------- main: single fused kernel -----------------------------------
// Round-4 structure: round-3's 256^2 counted-vmcnt pipeline + in-kernel A
// conversion (deletes the 83 us convert_pass + its 390 MB HBM round-trip).
// Why round-2's fused attempt failed and how each cause is fixed here:
//  (a) fp32 loads were synchronous before convert  -> T14 split: A(t+2) fp32
//      loads issued BEFORE compute(t); converted one half-iter later (~700 cy
//      of latency hiding). Compiler inserts the exact vmcnt before first use.
//  (b) 917K bank conflicts on swizzled ds_write    -> swizzle moved to the
//      GLOBAL source (chunk (lane&7)^(row&7)); LDS write is per-wave
//      contiguous base+lane*16 (conflict-free, same layout the reader expects).
//  (c) 128^2 2-barrier structure                   -> round-3 256^2 skeleton.
// Pipeline invariant at each half-iteration H(t) entry (after barrier):
//   outstanding VMEM = A(t+1) fp32 x8 (oldest) + B(t+1) gload_lds x4 (newest).
//   H(t): compute buf(t&1); [B1]; cvt A(t+1)->buf(~t&1) A-region (free since
//   H(t-1).[B1]); issue A(t+2) regs + B(t+2)->buf(t&1) B-region (free since
//   [B1]); vmcnt(12) => B(t+1) landed (12 newest = this half's issues);
//   lgkmcnt(0) => own ds_writes committed; [B2]. vmcnt is in-order counting,
//   so vmcnt(12) is an exact bound. Every LDS region written here is >= 2
//   barriers from its last reader (safe even if LLVM hoists one barrier).
__global__ __launch_bounds__(GTHREADS, 2) void fused_big(
    const float* __restrict__ mod0, const float* __restrict__ mod1,
    const float* __restrict__ mod2, const float* __restrict__ mod3,
    const ushort_t* __restrict__ Wb, float* __restrict__ out)
{
    __shared__ __align__(16) ushort_t As0[BM2 * BK];   // 32 KB
    __shared__ __align__(16) ushort_t Bs0[BN2 * BK];   // 32 KB
    __shared__ __align__(16) ushort_t As1[BM2 * BK];   // 32 KB
    __shared__ __align__(16) ushort_t Bs1[BN2 * BK];   // 32 KB
    __shared__ unsigned rowOr[BM2];
    __shared__ float scalerS[BM2 / 4];

    const int t    = threadIdx.x;
    const int lane = t & 63;
    const int wave = t >> 6;          // 0..7
    const int quad = lane >> 4;
    const int ln15 = lane & 15;
    const int wm   = wave >> 2;       // 0..1 : rows wm*128..+128
    const int wn   = wave & 3;        // 0..3 : cols wn*64..+64

    // T1: XCD-aware bijective remap. 1024 blocks, 8 XCDs, 1024 % 8 == 0.
    const int bid  = blockIdx.x;
    const int wid  = (bid & 7) * 128 + (bid >> 3);
    const int colb = wid & 3;
    const int rowb = wid >> 2;
    const int row0 = rowb * BM2;
    const int col0 = colb * BN2;

    if (t < BM2) rowOr[t] = 0u;

    // staging geometry: wave w, round q covers rows w*32 + q*8 + (lane>>3);
    // LDS slot = lane&7 (linear dest), global chunk = (lane&7)^(row&7).
    const int rloc = (lane >> 3);
    const int c8   = (lane & 7) ^ rloc;
    const float*    aFp[4];
    const ushort_t* bP[4];
    unsigned wrOff[4];   // ushort index for A ds_write_b128
    unsigned dstB[4];    // ushort index, wave-uniform base for B gload_lds
    unsigned orAcc[4] = {0u, 0u, 0u, 0u};
    #pragma unroll
    for (int q = 0; q < 4; ++q) {
        const int r  = wave * 32 + q * 8 + rloc;
        const int gr = row0 + r;
        const int bb = gr >> 2;
        const int mm = gr & 3;
        const float* mp = (mm == 0) ? mod0 : (mm == 1) ? mod1 : (mm == 2) ? mod2 : mod3;
        aFp[q] = mp + (size_t)bb * M_LEN + c8 * 8;
        bP[q]  = Wb + (size_t)(col0 + r) * M_LEN + c8 * 8;
        wrOff[q] = (unsigned)(r * 64 + (lane & 7) * 8);
        dstB[q]  = (unsigned)((wave * 32 + q * 8) * 64);
    }

    float4 aR[8];   // in-flight A fp32 tile fragment (one K-tile ahead in regs)

    // issue one K-tile of A fp32 loads into aR (8 x global_load_dwordx4)
    auto aIssue = [&]() {
        #pragma unroll
        for (int q = 0; q < 4; ++q) {
            const float4* pa = (const float4*)aFp[q];
            aR[2 * q]     = pa[0];
            aR[2 * q + 1] = pa[1];
            aFp[q] += BK;
        }
    };
    // convert aR -> bf16, accumulate zero-flags, ds_write_b128 (contiguous)
    auto aCvt = [&](ushort_t* dA) {
        #pragma unroll
        for (int q = 0; q < 4; ++q) {
            const float4 v0 = aR[2 * q], v1 = aR[2 * q + 1];
            orAcc[q] |= ((__float_as_uint(v0.x) | __float_as_uint(v0.y) |
                          __float_as_uint(v0.z) | __float_as_uint(v0.w) |
                          __float_as_uint(v1.x) | __float_as_uint(v1.y) |
                          __float_as_uint(v1.z) | __float_as_uint(v1.w)) << 1);
            unsigned p0, p1, p2, p3;   // RNE packed convert, 1 instr / 2 values
            asm("v_cvt_pk_bf16_f32 %0, %1, %2" : "=v"(p0) : "v"(v0.x), "v"(v0.y));
            asm("v_cvt_pk_bf16_f32 %0, %1, %2" : "=v"(p1) : "v"(v0.z), "v"(v0.w));
            asm("v_cvt_pk_bf16_f32 %0, %1, %2" : "=v"(p2) : "v"(v1.x), "v"(v1.y));
            asm("v_cvt_pk_bf16_f32 %0, %1, %2" : "=v"(p3) : "v"(v1.z), "v"(v1.w));
            *(uint4*)&dA[wrOff[q]] = make_uint4(p0, p1, p2, p3);
        }
    };
    // issue one K-tile of B async global->LDS (4 x global_load_lds_dwordx4)
    auto bIssue = [&](ushort_t* dB) {
        #pragma unroll
        for (int q = 0; q < 4; ++q) {
            gload_lds16(bP[q], dB + dstB[q]);
            bP[q] += BK;
        }
    };

    f32x4 acc[8][4];
    #pragma unroll
    for (int i = 0; i < 8; ++i)
        #pragma unroll
        for (int j = 0; j < 4; ++j)
            acc[i][j] = (f32x4){0.f, 0.f, 0.f, 0.f};

    const unsigned slotB   = (unsigned)(quad ^ (ln15 & 7));
    const unsigned aRowOff = (unsigned)((wm * 128 + ln15) * 64);
    const unsigned bRowOff = (unsigned)((wn * 64 + ln15) * 64);

    auto compute = [&](const ushort_t* As_, const ushort_t* Bs_) {
        #pragma unroll
        for (int ks = 0; ks < 2; ++ks) {
            const unsigned slot8 = (slotB ^ (unsigned)(ks * 4)) * 8u;
            bf16x8 af[8], bfr[4];
            #pragma unroll
            for (int i = 0; i < 8; ++i)
                af[i] = *(const bf16x8*)(&As_[aRowOff + i * 1024 + slot8]);
            #pragma unroll
            for (int j = 0; j < 4; ++j)
                bfr[j] = *(const bf16x8*)(&Bs_[bRowOff + j * 1024 + slot8]);
            #pragma unroll
            for (int i = 0; i < 8; ++i)
                #pragma unroll
                for (int j = 0; j < 4; ++j)
                    acc[i][j] = __builtin_amdgcn_mfma_f32_16x16x32_bf16(
                        af[i], bfr[j], acc[i][j], 0, 0, 0);
        }
    };

    // ---- prologue: A0 cvt'd into As0; A1 in regs; B0/B1 in flight ----
    aIssue();                 // A0 -> aR
    bIssue(Bs0);              // B0
    aCvt(As0);                // compiler waits exactly for A0 (vmcnt(4))
    aIssue();                 // A1 -> aR
    bIssue(Bs1);              // B1
    asm volatile("s_waitcnt vmcnt(12)" ::: "memory");   // B0 landed
    asm volatile("s_waitcnt lgkmcnt(0)" ::: "memory");  // As0 writes done
    __builtin_amdgcn_s_barrier();
    asm volatile("" ::: "memory");

    // ---- steady state: H(0)..H(13) ----
    #pragma unroll 1
    for (int it = 0; it < 7; ++it) {
        // H(2it): tile even from buf0
        compute(As0, Bs0);
        __builtin_amdgcn_s_barrier();
        asm volatile("" ::: "memory");
        aCvt(As1);            // A(t+1) -> buf1 (free since previous [B1])
        aIssue();             // A(t+2) fp32 -> regs
        bIssue(Bs0);          // B(t+2) -> buf0 (free since this [B1])
        asm volatile("s_waitcnt vmcnt(12)" ::: "memory");  // B(t+1) landed
        asm volatile("s_waitcnt lgkmcnt(0)" ::: "memory"); // own A writes done
        __builtin_amdgcn_s_barrier();
        asm volatile("" ::: "memory");

        // H(2it+1): tile odd from buf1
        compute(As1, Bs1);
        __builtin_amdgcn_s_barrier();
        asm volatile("" ::: "memory");
        aCvt(As0);
        aIssue();
        bIssue(Bs1);
        asm volatile("s_waitcnt vmcnt(12)" ::: "memory");
        asm volatile("s_waitcnt lgkmcnt(0)" ::: "memory");
        __builtin_amdgcn_s_barrier();
        asm volatile("" ::: "memory");
    }

    // ---- tail: H(14) (no new issues), H(15) ----
    compute(As0, Bs0);                                  // tile 14
    __builtin_amdgcn_s_barrier();
    asm volatile("" ::: "memory");
    aCvt(As1);                                          // A15 (compiler waits)
    asm volatile("s_waitcnt vmcnt(0)" ::: "memory");    // B15 landed
    asm volatile("s_waitcnt lgkmcnt(0)" ::: "memory");
    __builtin_amdgcn_s_barrier();
    asm volatile("" ::: "memory");
    compute(As1, Bs1);                                  // tile 15

    // ---- zero-row flags -> per-patient scaler ----
    #pragma unroll
    for (int q = 0; q < 4; ++q)
        atomicOr(&rowOr[wave * 32 + q * 8 + rloc], orAcc[q]);
    __syncthreads();
    if (t < 64) {
        const int z = (rowOr[4 * t + 0] == 0u) + (rowOr[4 * t + 1] == 0u)
                    + (rowOr[4 * t + 2] == 0u) + (rowOr[4 * t + 3] == 0u);
        scalerS[t] = (z > 0) ? (float)(z + 1) : 1.0f;
    }
    __syncthreads();

    // ---- epilogue: modality softmax + weighted fp32 sum + scaler, nt-store ----
    // C/D 16x16: col = ln15, row = quad*4 + reg; A rows (4b+m) -> reg == modality.
    #pragma unroll
    for (int i = 0; i < 8; ++i) {
        const int bl = wm * 32 + i * 4 + quad;
        const int b  = rowb * 64 + bl;
        const float scal = scalerS[bl];
        #pragma unroll
        for (int j = 0; j < 4; ++j) {
            const int k = col0 + wn * 64 + j * 16 + ln15;
            const size_t off = (size_t)b * M_LEN + k;
            const float x0 = mod0[off], x1 = mod1[off];
            const float x2 = mod2[off], x3 = mod3[off];
            const f32x4 s = acc[i][j];
            const float mx = fmaxf(fmaxf(s.x, s.y), fmaxf(s.z, s.w));
            const float e0 = __expf(s.x - mx);
            const float e1 = __expf(s.y - mx);
            const float e2 = __expf(s.z - mx);
            const float e3 = __expf(s.w - mx);
            const float num = e0 * x0 + e1 * x1 + e2 * x2 + e3 * x3;
            const float v = num * scal / (e0 + e1 + e2 + e3);
            __builtin_nontemporal_store(v, &out[off]);
        }
    }
}

// ---------------- fallback: single fused kernel (used if ws too small) ----------
__global__ __launch_bounds__(THREADS) void fused_modal_attn(
    const float* __restrict__ mod0, const float* __restrict__ mod1,
    const float* __restrict__ mod2, const float* __restrict__ mod3,
    const float* __restrict__ W, float* __restrict__ out)
{
    __shared__ __align__(16) unsigned short As[BM * BK];
    __shared__ __align__(16) unsigned short Bs[BN * BK];
    __shared__ unsigned rowOr[BM];
    __shared__ float scalerS[BM / 4];

    const int t    = threadIdx.x;
    const int lane = t & 63;
    const int wave = t >> 6;
    const int quad = lane >> 4;
    const int ln15 = lane & 15;
    const int wm   = wave >> 1;
    const int wn   = wave & 1;

    const int colb = blockIdx.x;
    const int rowb = blockIdx.y;
    const int row0 = rowb * BM;
    const int col0 = colb * BN;

    if (t < BM) rowOr[t] = 0u;

    const int sr  = t >> 3;
    const int scl = t & 7;

    const float* ap[4];
    const float* bp[4];
    unsigned ldsOff[4];
    unsigned orAcc[4] = {0u, 0u, 0u, 0u};
    #pragma unroll
    for (int j = 0; j < 4; ++j) {
        const int r  = j * 32 + sr;
        const int gr = row0 + r;
        const int b  = gr >> 2;
        const int m  = gr & 3;
        const float* mp = (m == 0) ? mod0 : (m == 1) ? mod1 : (m == 2) ? mod2 : mod3;
        ap[j] = mp + (size_t)b * M_LEN + scl * 8;
        bp[j] = W + (size_t)(col0 + r) * M_LEN + scl * 8;
        ldsOff[j] = (unsigned)(r * 64 + ((scl ^ (r & 7)) * 8));
    }

    f32x4 acc[4][4];
    #pragma unroll
    for (int i = 0; i < 4; ++i)
        #pragma unroll
        for (int j = 0; j < 4; ++j)
            acc[i][j] = (f32x4){0.f, 0.f, 0.f, 0.f};

    const unsigned slotB   = (unsigned)(quad ^ (ln15 & 7));
    const unsigned aRowOff = (unsigned)((wm * 64 + ln15) * 64);
    const unsigned bRowOff = (unsigned)((wn * 64 + ln15) * 64);

    for (int it = 0; it < 16; ++it) {
        __syncthreads();
        #pragma unroll
        for (int j = 0; j < 4; ++j) {
            const float4* pa = (const float4*)ap[j];
            const float4* pb = (const float4*)bp[j];
            float4 a0 = pa[0], a1 = pa[1];
            float4 b0 = pb[0], b1 = pb[1];
            ap[j] += BK; bp[j] += BK;

            unsigned pA0 = pack2(a0.x, a0.y), pA1 = pack2(a0.z, a0.w);
            unsigned pA2 = pack2(a1.x, a1.y), pA3 = pack2(a1.z, a1.w);
            orAcc[j] |= (pA0 | pA1) | (pA2 | pA3);
            *(uint4*)(&As[ldsOff[j]]) = make_uint4(pA0, pA1, pA2, pA3);

            unsigned pB0 = pack2(b0.x, b0.y), pB1 = pack2(b0.z, b0.w);
            unsigned pB2 = pack2(b1.x, b1.y), pB3 = pack2(b1.z, b1.w);
            *(uint4*)(&Bs[ldsOff[j]]) = make_uint4(pB0, pB1, pB2, pB3);
        }
        __syncthreads();
        #pragma unroll
        for (int ks = 0; ks < 2; ++ks) {
            const unsigned slot8 = (slotB ^ (unsigned)(ks * 4)) * 8u;
            bf16x8 af[4], bfr[4];
            #pragma unroll
            for (int i = 0; i < 4; ++i)
                af[i] = *(const bf16x8*)(&As[aRowOff + i * 1024 + slot8]);
            #pragma unroll
            for (int j = 0; j < 4; ++j)
                bfr[j] = *(const bf16x8*)(&Bs[bRowOff + j * 1024 + slot8]);
            #pragma unroll
            for (int i = 0; i < 4; ++i)
                #pragma unroll
                for (int j = 0; j < 4; ++j)
                    acc[i][j] = __builtin_amdgcn_mfma_f32_16x16x32_bf16(
                        af[i], bfr[j], acc[i][j], 0, 0, 0);
        }
    }

    #pragma unroll
    for (int j = 0; j < 4; ++j)
        atomicOr(&rowOr[j * 32 + sr], orAcc[j]);
    __syncthreads();
    if (t < 32) {
        const int z = (rowOr[4 * t + 0] == 0u) + (rowOr[4 * t + 1] == 0u)
                    + (rowOr[4 * t + 2] == 0u) + (rowOr[4 * t + 3] == 0u);
        scalerS[t] = (z > 0) ? (float)(z + 1) : 1.0f;
    }
    __syncthreads();

    #pragma unroll
    for (int i = 0; i < 4; ++i) {
        const int bl = wm * 16 + i * 4 + quad;
        const int b  = rowb * 32 + bl;
        const float scal = scalerS[bl];
        #pragma unroll
        for (int j = 0; j < 4; ++j) {
            const int k = col0 + wn * 64 + j * 16 + ln15;
            const size_t off = (size_t)b * M_LEN + k;
            const float x0 = mod0[off], x1 = mod1[off];
            const float x2 = mod2[off], x3 = mod3[off];
            const f32x4 s = acc[i][j];
            const float mx = fmaxf(fmaxf(s.x, s.y), fmaxf(s.z, s.w));
            const float e0 = __expf(s.x - mx);
            const float e1 = __expf(s.y - mx);
            const float e2 = __expf(s.z - mx);
            const float e3 = __expf(s.w - mx);
            const float num = e0 * x0 + e1 * x1 + e2 * x2 + e3 * x3;
            out[off] = num * scal / (e0 + e1 + e2 + e3);
        }
    }
}

// ---------------- launch ----------------
extern "C" void kernel_launch(void* const* d_in, const int* in_sizes, int n_in,
                              void* d_out, int out_size, void* d_ws, size_t ws_size,
                              hipStream_t stream) {
    const float* mod0 = (const float*)d_in[0];
    const float* mod1 = (const float*)d_in[1];
    const float* mod2 = (const float*)d_in[2];
    const float* mod3 = (const float*)d_in[3];
    const float* W    = (const float*)d_in[4];
    float* out = (float*)d_out;

    // workspace: W bf16 only (2 MiB)
    const size_t wbBytes = (size_t)M_LEN * M_LEN * sizeof(ushort_t);

    if (ws_size >= wbBytes) {
        ushort_t* Wb = (ushort_t*)d_ws;
        convert_w<<<dim3(M_LEN / 4), dim3(THREADS), 0, stream>>>(W, Wb);
        // 1024 blocks (4 colb x 256 rowb), T1 swizzle inside the kernel
        fused_big<<<dim3((M_LEN / BN2) * ((4 * BATCH) / BM2)), dim3(GTHREADS), 0, stream>>>(
            mod0, mod1, mod2, mod3, Wb, out);
    } else {
        dim3 grid(M_LEN / BN, (4 * BATCH) / BM);
        fused_modal_attn<<<grid, dim3(THREADS), 0, stream>>>(
            mod0, mod1, mod2, mod3, W, out);
    }
}

// Round 5
// 374.325 us; speedup vs baseline: 1.6191x; 1.6191x over previous
//
#include <hip/hip_runtime.h>
#include <hip/hip_bf16.h>

#define M_LEN 1024
#define BATCH 16384

// fallback kernel tiling
#define BM 128
#define BN 128
#define BK 64
#define THREADS 256

// main gemm tiling (256^2, 8 waves, K-step 32, triple-buffered)
#define BM2 256
#define BN2 256
#define BK2 32
#define GTHREADS 512

typedef __attribute__((ext_vector_type(8))) short bf16x8;
typedef __attribute__((ext_vector_type(4))) float f32x4;
typedef unsigned short ushort_t;

// ---------------- helpers ----------------

// fp32 -> bf16 RNE
__device__ __forceinline__ ushort_t bf16_rne(float f) {
    unsigned u = __float_as_uint(f);
    unsigned r = u + 0x7FFFu + ((u >> 16) & 1u);
    return (ushort_t)(r >> 16);
}

__device__ __forceinline__ float bf16_to_f(ushort_t u) {
    return __uint_as_float(((unsigned)u) << 16);
}

// pack two fp32 -> two bf16 (RTZ) in one v_perm_b32 (fallback kernel only)
__device__ __forceinline__ unsigned pack2(float lo, float hi) {
    return __builtin_amdgcn_perm(__float_as_uint(hi), __float_as_uint(lo), 0x07060302u);
}

// async global->LDS, 16B per lane. LDS dest is wave-uniform base + lane*16.
__device__ __forceinline__ void gload_lds16(const void* g, void* l) {
    __builtin_amdgcn_global_load_lds(
        (const __attribute__((address_space(1))) unsigned int*)g,
        (__attribute__((address_space(3))) unsigned int*)l,
        16, 0, 0);
}

// non-temporal 16B load
__device__ __forceinline__ float4 ntload4(const float4* p) {
    f32x4 v = __builtin_nontemporal_load((const f32x4*)p);
    return make_float4(v.x, v.y, v.z, v.w);
}

// ---------------- pass 1: fp32 -> bf16 conversion + zero-row flags ----------------
// ~83 us, at its streaming roofline (back-solved R0-R4) — unchanged since R0.
__global__ __launch_bounds__(THREADS) void convert_pass(
    const float* __restrict__ mod0, const float* __restrict__ mod1,
    const float* __restrict__ mod2, const float* __restrict__ mod3,
    const float* __restrict__ W,
    ushort_t* __restrict__ Ab, ushort_t* __restrict__ Wb, int* __restrict__ zf)
{
    const int blk  = blockIdx.x;
    const int wave = threadIdx.x >> 6;
    const int lane = threadIdx.x & 63;

    if (blk < BATCH) {
        const int b = blk, m = wave;
        const float* mp = (m == 0) ? mod0 : (m == 1) ? mod1 : (m == 2) ? mod2 : mod3;
        const float4* row = (const float4*)(mp + (size_t)b * M_LEN);
        ushort_t* dst = Ab + ((size_t)b * 4 + m) * M_LEN;
        unsigned orr = 0u;
        #pragma unroll
        for (int j = 0; j < 4; ++j) {
            float4 v = ntload4(&row[j * 64 + lane]);
            orr |= (__float_as_uint(v.x) | __float_as_uint(v.y) |
                    __float_as_uint(v.z) | __float_as_uint(v.w)) << 1;  // drop signs
            ushort4 o;
            o.x = bf16_rne(v.x); o.y = bf16_rne(v.y);
            o.z = bf16_rne(v.z); o.w = bf16_rne(v.w);
            ((ushort4*)dst)[j * 64 + lane] = o;
        }
        const int nz = __any(orr != 0u);
        if (lane == 0) zf[b * 4 + m] = nz ? 0 : 1;
    } else {
        const int r = (blk - BATCH) * 4 + wave;
        const float4* row = (const float4*)(W + (size_t)r * M_LEN);
        ushort_t* dst = Wb + (size_t)r * M_LEN;
        #pragma unroll
        for (int j = 0; j < 4; ++j) {
            float4 v = row[j * 64 + lane];
            ushort4 o;
            o.x = bf16_rne(v.x); o.y = bf16_rne(v.y);
            o.z = bf16_rne(v.z); o.w = bf16_rne(v.w);
            ((ushort4*)dst)[j * 64 + lane] = o;
        }
    }
}

// ---------------- pass 2: 256^2 GEMM, phase-interleaved triple-buffer ------------
// Round-5 structure. BK=32, 3 LDS buffers per operand (96 KB): computing tile t
// from buf t%3 while staging tile t+2 into buf (t+2)%3 -> stage target is NEVER
// the buffer being read, so gload issues sit INSIDE the compute phases (the
// overlap round-3's 2-buffer scheme structurally forbade; its 3 streams ran
// serial: 2480cy MFMA + 2300cy ds_read + ~1000cy staging = measured 6600cy/tile).
// Per tile: 2 phases {ds_read || 2 gloads -> setprio(1) 16 MFMA setprio(0)},
// mini-barrier between, then vmcnt(4)+barrier at tile end.
// Sync invariant (identical to verified round-3): at each tile-end barrier,
// only the newest 4 VMEM ops (this tile's stage issues) may be outstanding;
// vmcnt(4) forces tile-(t+1)'s staging (issued last tile) complete, barrier
// makes it collective. Buf (t+2)%3's last readers finished at tile-(t-1)'s end
// barrier, strictly before this tile's stage issues. No hand lgkmcnt: ds_reads
// are plain derefs, compiler inserts exact waits (rule #18 avoided).
__global__ __launch_bounds__(GTHREADS, 2) void gemm_8p(
    const ushort_t* __restrict__ Ab, const ushort_t* __restrict__ Wb,
    const int* __restrict__ zf, float* __restrict__ out)
{
    __shared__ __align__(16) ushort_t AsB[3][BM2 * BK2];   // 3 x 16 KB
    __shared__ __align__(16) ushort_t BsB[3][BN2 * BK2];   // 3 x 16 KB
    __shared__ float scalerS[BM2 / 4];

    const int t    = threadIdx.x;
    const int lane = t & 63;
    const int wave = t >> 6;          // 0..7
    const int quad = lane >> 4;
    const int ln15 = lane & 15;
    const int wm   = wave >> 2;       // 0..1 : rows wm*128..+128
    const int wn   = wave & 3;        // 0..3 : cols wn*64..+64

    // T1: XCD-aware bijective remap. 1024 blocks, 8 XCDs, 1024 % 8 == 0.
    const int bid  = blockIdx.x;
    const int wid  = (bid & 7) * 128 + (bid >> 3);
    const int colb = wid & 3;
    const int rowb = wid >> 2;
    const int row0 = rowb * BM2;
    const int col0 = colb * BN2;

    if (t < 64) {
        const int4 f = ((const int4*)zf)[rowb * 64 + t];
        const int z = f.x + f.y + f.z + f.w;
        scalerS[t] = (z > 0) ? (float)(z + 1) : 1.0f;
    }

    // staging: wave w, gload g covers rows w*32 + g*16 + (lane>>2);
    // LDS slot = lane&3 (linear dest), global chunk = (lane&3)^(row&3).
    const int rloc = lane >> 2;                 // 0..15
    const int c4   = (lane & 3) ^ (rloc & 3);
    const ushort_t* aP[2];
    const ushort_t* bP[2];
    unsigned dstOff[2];
    #pragma unroll
    for (int g = 0; g < 2; ++g) {
        const int r = wave * 32 + g * 16 + rloc;
        aP[g] = Ab + (size_t)(row0 + r) * M_LEN + c4 * 8;
        bP[g] = Wb + (size_t)(col0 + r) * M_LEN + c4 * 8;
        dstOff[g] = (unsigned)((wave * 32 + g * 16) * BK2);   // ushort units
    }

    f32x4 acc[8][4];
    #pragma unroll
    for (int i = 0; i < 8; ++i)
        #pragma unroll
        for (int j = 0; j < 4; ++j)
            acc[i][j] = (f32x4){0.f, 0.f, 0.f, 0.f};

    // reader: row rho, global chunk q -> LDS slot q^(rho&3) (matches writer)
    const unsigned slotOff = (unsigned)((quad ^ (ln15 & 3)) * 8);
    const unsigned aRowOff = (unsigned)((wm * 128 + ln15) * BK2);
    const unsigned bRowOff = (unsigned)((wn * 64 + ln15) * BK2);

    // one tile: 2 phases, stage interleaved; ends BEFORE the tile-end sync
    auto tile_body = [&](const ushort_t* cA, const ushort_t* cB,
                         ushort_t* sA, ushort_t* sB, bool stage) {
        bf16x8 af[4], bfr[4];
        // ---- phase 0: B frags + A rows 0..63, stage 2 A-gloads, 16 MFMA ----
        #pragma unroll
        for (int j = 0; j < 4; ++j)
            bfr[j] = *(const bf16x8*)&cB[bRowOff + j * 16 * BK2 + slotOff];
        #pragma unroll
        for (int i = 0; i < 4; ++i)
            af[i] = *(const bf16x8*)&cA[aRowOff + i * 16 * BK2 + slotOff];
        if (stage) {
            #pragma unroll
            for (int g = 0; g < 2; ++g) {
                gload_lds16(aP[g], sA + dstOff[g]);
                aP[g] += BK2;
            }
        }
        __builtin_amdgcn_s_setprio(1);
        #pragma unroll
        for (int i = 0; i < 4; ++i)
            #pragma unroll
            for (int j = 0; j < 4; ++j)
                acc[i][j] = __builtin_amdgcn_mfma_f32_16x16x32_bf16(
                    af[i], bfr[j], acc[i][j], 0, 0, 0);
        __builtin_amdgcn_s_setprio(0);
        __builtin_amdgcn_s_barrier();
        // ---- phase 1: A rows 64..127, stage 2 B-gloads, 16 MFMA ----
        #pragma unroll
        for (int i = 0; i < 4; ++i)
            af[i] = *(const bf16x8*)&cA[aRowOff + (4 + i) * 16 * BK2 + slotOff];
        if (stage) {
            #pragma unroll
            for (int g = 0; g < 2; ++g) {
                gload_lds16(bP[g], sB + dstOff[g]);
                bP[g] += BK2;
            }
        }
        __builtin_amdgcn_s_setprio(1);
        #pragma unroll
        for (int i = 0; i < 4; ++i)
            #pragma unroll
            for (int j = 0; j < 4; ++j)
                acc[4 + i][j] = __builtin_amdgcn_mfma_f32_16x16x32_bf16(
                    af[i], bfr[j], acc[4 + i][j], 0, 0, 0);
        __builtin_amdgcn_s_setprio(0);
    };

    ushort_t *A0 = AsB[0], *A1 = AsB[1], *A2 = AsB[2];
    ushort_t *B0 = BsB[0], *B1 = BsB[1], *B2 = BsB[2];

    // prologue: stage t0 -> buf0, t1 -> buf1 (4 gloads each)
    #pragma unroll
    for (int g = 0; g < 2; ++g) { gload_lds16(aP[g], A0 + dstOff[g]); aP[g] += BK2; }
    #pragma unroll
    for (int g = 0; g < 2; ++g) { gload_lds16(bP[g], B0 + dstOff[g]); bP[g] += BK2; }
    #pragma unroll
    for (int g = 0; g < 2; ++g) { gload_lds16(aP[g], A1 + dstOff[g]); aP[g] += BK2; }
    #pragma unroll
    for (int g = 0; g < 2; ++g) { gload_lds16(bP[g], B1 + dstOff[g]); bP[g] += BK2; }
    asm volatile("s_waitcnt vmcnt(4) lgkmcnt(0)" ::: "memory");   // t0 + scalerS done
    __builtin_amdgcn_s_barrier();

    // tiles 0..29: full body, staging tiles 2..31
    #pragma unroll 1
    for (int kt = 0; kt < 30; ++kt) {
        tile_body(A0, B0, A2, B2, true);
        asm volatile("s_waitcnt vmcnt(4)" ::: "memory");   // tile kt+1 landed
        __builtin_amdgcn_s_barrier();
        ushort_t* x;
        x = A0; A0 = A1; A1 = A2; A2 = x;
        x = B0; B0 = B1; B1 = B2; B2 = x;
    }
    // tile 30: no staging; wait tile 31
    tile_body(A0, B0, (ushort_t*)0, (ushort_t*)0, false);
    asm volatile("s_waitcnt vmcnt(0)" ::: "memory");
    __builtin_amdgcn_s_barrier();
    // tile 31
    tile_body(A1, B1, (ushort_t*)0, (ushort_t*)0, false);

    // ---- epilogue: modality softmax + weighted sum + scaler, nt-store ----
    // C/D 16x16: col = ln15, row = quad*4 + reg; A rows (4b+m) -> reg == modality.
    // x read as bf16 from Ab (L3-resident, same values the GEMM used).
    #pragma unroll
    for (int i = 0; i < 8; ++i) {
        const int bl = wm * 32 + i * 4 + quad;
        const int b  = rowb * 64 + bl;
        const float scal = scalerS[bl];
        const ushort_t* xr = Ab + (size_t)b * 4 * M_LEN;   // row 4b (modality 0)
        #pragma unroll
        for (int j = 0; j < 4; ++j) {
            const int k = col0 + wn * 64 + j * 16 + ln15;
            const float x0 = bf16_to_f(xr[k]);
            const float x1 = bf16_to_f(xr[M_LEN + k]);
            const float x2 = bf16_to_f(xr[2 * M_LEN + k]);
            const float x3 = bf16_to_f(xr[3 * M_LEN + k]);
            const f32x4 s = acc[i][j];
            const float mx = fmaxf(fmaxf(s.x, s.y), fmaxf(s.z, s.w));
            const float e0 = __expf(s.x - mx);
            const float e1 = __expf(s.y - mx);
            const float e2 = __expf(s.z - mx);
            const float e3 = __expf(s.w - mx);
            const float num = e0 * x0 + e1 * x1 + e2 * x2 + e3 * x3;
            const float v = num * scal / (e0 + e1 + e2 + e3);
            __builtin_nontemporal_store(v, &out[(size_t)b * M_LEN + k]);
        }
    }
}

// ---------------- fallback: single fused kernel (used if ws too small) ----------
__global__ __launch_bounds__(THREADS) void fused_modal_attn(
    const float* __restrict__ mod0, const float* __restrict__ mod1,
    const float* __restrict__ mod2, const float* __restrict__ mod3,
    const float* __restrict__ W, float* __restrict__ out)
{
    __shared__ __align__(16) unsigned short As[BM * BK];
    __shared__ __align__(16) unsigned short Bs[BN * BK];
    __shared__ unsigned rowOr[BM];
    __shared__ float scalerS[BM / 4];

    const int t    = threadIdx.x;
    const int lane = t & 63;
    const int wave = t >> 6;
    const int quad = lane >> 4;
    const int ln15 = lane & 15;
    const int wm   = wave >> 1;
    const int wn   = wave & 1;

    const int colb = blockIdx.x;
    const int rowb = blockIdx.y;
    const int row0 = rowb * BM;
    const int col0 = colb * BN;

    if (t < BM) rowOr[t] = 0u;

    const int sr  = t >> 3;
    const int scl = t & 7;

    const float* ap[4];
    const float* bp[4];
    unsigned ldsOff[4];
    unsigned orAcc[4] = {0u, 0u, 0u, 0u};
    #pragma unroll
    for (int j = 0; j < 4; ++j) {
        const int r  = j * 32 + sr;
        const int gr = row0 + r;
        const int b  = gr >> 2;
        const int m  = gr & 3;
        const float* mp = (m == 0) ? mod0 : (m == 1) ? mod1 : (m == 2) ? mod2 : mod3;
        ap[j] = mp + (size_t)b * M_LEN + scl * 8;
        bp[j] = W + (size_t)(col0 + r) * M_LEN + scl * 8;
        ldsOff[j] = (unsigned)(r * 64 + ((scl ^ (r & 7)) * 8));
    }

    f32x4 acc[4][4];
    #pragma unroll
    for (int i = 0; i < 4; ++i)
        #pragma unroll
        for (int j = 0; j < 4; ++j)
            acc[i][j] = (f32x4){0.f, 0.f, 0.f, 0.f};

    const unsigned slotB   = (unsigned)(quad ^ (ln15 & 7));
    const unsigned aRowOff = (unsigned)((wm * 64 + ln15) * 64);
    const unsigned bRowOff = (unsigned)((wn * 64 + ln15) * 64);

    for (int it = 0; it < 16; ++it) {
        __syncthreads();
        #pragma unroll
        for (int j = 0; j < 4; ++j) {
            const float4* pa = (const float4*)ap[j];
            const float4* pb = (const float4*)bp[j];
            float4 a0 = pa[0], a1 = pa[1];
            float4 b0 = pb[0], b1 = pb[1];
            ap[j] += BK; bp[j] += BK;

            unsigned pA0 = pack2(a0.x, a0.y), pA1 = pack2(a0.z, a0.w);
            unsigned pA2 = pack2(a1.x, a1.y), pA3 = pack2(a1.z, a1.w);
            orAcc[j] |= (pA0 | pA1) | (pA2 | pA3);
            *(uint4*)(&As[ldsOff[j]]) = make_uint4(pA0, pA1, pA2, pA3);

            unsigned pB0 = pack2(b0.x, b0.y), pB1 = pack2(b0.z, b0.w);
            unsigned pB2 = pack2(b1.x, b1.y), pB3 = pack2(b1.z, b1.w);
            *(uint4*)(&Bs[ldsOff[j]]) = make_uint4(pB0, pB1, pB2, pB3);
        }
        __syncthreads();
        #pragma unroll
        for (int ks = 0; ks < 2; ++ks) {
            const unsigned slot8 = (slotB ^ (unsigned)(ks * 4)) * 8u;
            bf16x8 af[4], bfr[4];
            #pragma unroll
            for (int i = 0; i < 4; ++i)
                af[i] = *(const bf16x8*)(&As[aRowOff + i * 1024 + slot8]);
            #pragma unroll
            for (int j = 0; j < 4; ++j)
                bfr[j] = *(const bf16x8*)(&Bs[bRowOff + j * 1024 + slot8]);
            #pragma unroll
            for (int i = 0; i < 4; ++i)
                #pragma unroll
                for (int j = 0; j < 4; ++j)
                    acc[i][j] = __builtin_amdgcn_mfma_f32_16x16x32_bf16(
                        af[i], bfr[j], acc[i][j], 0, 0, 0);
        }
    }

    #pragma unroll
    for (int j = 0; j < 4; ++j)
        atomicOr(&rowOr[j * 32 + sr], orAcc[j]);
    __syncthreads();
    if (t < 32) {
        const int z = (rowOr[4 * t + 0] == 0u) + (rowOr[4 * t + 1] == 0u)
                    + (rowOr[4 * t + 2] == 0u) + (rowOr[4 * t + 3] == 0u);
        scalerS[t] = (z > 0) ? (float)(z + 1) : 1.0f;
    }
    __syncthreads();

    #pragma unroll
    for (int i = 0; i < 4; ++i) {
        const int bl = wm * 16 + i * 4 + quad;
        const int b  = rowb * 32 + bl;
        const float scal = scalerS[bl];
        #pragma unroll
        for (int j = 0; j < 4; ++j) {
            const int k = col0 + wn * 64 + j * 16 + ln15;
            const size_t off = (size_t)b * M_LEN + k;
            const float x0 = mod0[off], x1 = mod1[off];
            const float x2 = mod2[off], x3 = mod3[off];
            const f32x4 s = acc[i][j];
            const float mx = fmaxf(fmaxf(s.x, s.y), fmaxf(s.z, s.w));
            const float e0 = __expf(s.x - mx);
            const float e1 = __expf(s.y - mx);
            const float e2 = __expf(s.z - mx);
            const float e3 = __expf(s.w - mx);
            const float num = e0 * x0 + e1 * x1 + e2 * x2 + e3 * x3;
            out[off] = num * scal / (e0 + e1 + e2 + e3);
        }
    }
}

// ---------------- launch ----------------
extern "C" void kernel_launch(void* const* d_in, const int* in_sizes, int n_in,
                              void* d_out, int out_size, void* d_ws, size_t ws_size,
                              hipStream_t stream) {
    const float* mod0 = (const float*)d_in[0];
    const float* mod1 = (const float*)d_in[1];
    const float* mod2 = (const float*)d_in[2];
    const float* mod3 = (const float*)d_in[3];
    const float* W    = (const float*)d_in[4];
    float* out = (float*)d_out;

    // workspace layout: A' bf16 (128 MiB) | W bf16 (2 MiB) | zf int[65536] (256 KiB)
    const size_t abBytes = (size_t)4 * BATCH * M_LEN * sizeof(ushort_t);
    const size_t wbBytes = (size_t)M_LEN * M_LEN * sizeof(ushort_t);
    const size_t zfBytes = (size_t)4 * BATCH * sizeof(int);
    const size_t need = abBytes + wbBytes + zfBytes;

    if (ws_size >= need) {
        ushort_t* Ab = (ushort_t*)d_ws;
        ushort_t* Wb = (ushort_t*)((char*)d_ws + abBytes);
        int*      zfp = (int*)((char*)d_ws + abBytes + wbBytes);

        convert_pass<<<dim3(BATCH + M_LEN / 4), dim3(THREADS), 0, stream>>>(
            mod0, mod1, mod2, mod3, W, Ab, Wb, zfp);

        // 1024 blocks (4 colb x 256 rowb), T1 swizzle inside the kernel
        gemm_8p<<<dim3((M_LEN / BN2) * ((4 * BATCH) / BM2)), dim3(GTHREADS), 0, stream>>>(
            Ab, Wb, zfp, out);
    } else {
        dim3 grid(M_LEN / BN, (4 * BATCH) / BM);
        fused_modal_attn<<<grid, dim3(THREADS), 0, stream>>>(
            mod0, mod1, mod2, mod3, W, out);
    }
}